// Round 1
// baseline (634.381 us; speedup 1.0000x reference)
//
#include <hip/hip_runtime.h>
#include <stdint.h>
#include <math.h>

#define T_TOK 4096
#define H_DIM 1024
#define I_DIM 2048
#define E_NUM 8

typedef __attribute__((ext_vector_type(8))) short short8;
typedef __attribute__((ext_vector_type(4))) float f32x4;
typedef unsigned short u16;
typedef unsigned int u32;

__device__ __forceinline__ u16 f2bf(float f) {
  union { float f; u32 u; } v; v.f = f;
  u32 r = v.u + 0x7fffu + ((v.u >> 16) & 1u);  // round-to-nearest-even
  return (u16)(r >> 16);
}

// ---------------- zero init (d_out final region + counts) ----------------
__global__ void zero_kernel(float* __restrict__ out, int n4, int* __restrict__ counts) {
  int i = blockIdx.x * blockDim.x + threadIdx.x;
  int stride = gridDim.x * blockDim.x;
  float4 z = make_float4(0.f, 0.f, 0.f, 0.f);
  for (int j = i; j < n4; j += stride) ((float4*)out)[j] = z;
  if (blockIdx.x == 0 && threadIdx.x < E_NUM) counts[threadIdx.x] = 0;
}

// ---------------- x fp32 -> bf16 ----------------
__global__ void cvt_x_kernel(const float* __restrict__ x, u16* __restrict__ xb, int n4) {
  int i = blockIdx.x * blockDim.x + threadIdx.x;
  int stride = gridDim.x * blockDim.x;
  for (int j = i; j < n4; j += stride) {
    float4 v = ((const float4*)x)[j];
    ushort4 o;
    o.x = f2bf(v.x); o.y = f2bf(v.y); o.z = f2bf(v.z); o.w = f2bf(v.w);
    ((ushort4*)xb)[j] = o;
  }
}

// ---------------- transpose + convert: src [R][C] fp32 -> dst [C][R] bf16, batched over E ----------------
__global__ void tconv_kernel(const float* __restrict__ src, u16* __restrict__ dst, int R, int C) {
  __shared__ float tile[32][33];
  const float* s = src + (size_t)blockIdx.z * R * C;
  u16* d = dst + (size_t)blockIdx.z * R * C;
  int c0 = blockIdx.x * 32, r0 = blockIdx.y * 32;
  for (int i = threadIdx.y; i < 32; i += 8)
    tile[i][threadIdx.x] = s[(size_t)(r0 + i) * C + c0 + threadIdx.x];
  __syncthreads();
  for (int i = threadIdx.y; i < 32; i += 8)
    d[(size_t)(c0 + i) * R + r0 + threadIdx.x] = f2bf(tile[threadIdx.x][i]);
}

// ---------------- router: logits, softmax, top-2 (one wave per token) ----------------
__global__ void router_kernel(const float* __restrict__ x, const float* __restrict__ gw,
                              float* __restrict__ logits_out, int* __restrict__ counts,
                              int* __restrict__ te, float* __restrict__ tw) {
  const int wave = threadIdx.x >> 6, lane = threadIdx.x & 63;
  const int t = blockIdx.x * 4 + wave;
  const float* xr = x + (size_t)t * H_DIM;
  float acc[8];
#pragma unroll
  for (int e = 0; e < 8; e++) acc[e] = 0.f;
#pragma unroll
  for (int it = 0; it < 4; it++) {
    int h0 = it * 256 + lane * 4;
    float4 xv = *(const float4*)(xr + h0);
#pragma unroll
    for (int j = 0; j < 4; j++) {
      float xs = (j == 0) ? xv.x : (j == 1) ? xv.y : (j == 2) ? xv.z : xv.w;
      float4 g0 = *(const float4*)(gw + (size_t)(h0 + j) * 8);
      float4 g1 = *(const float4*)(gw + (size_t)(h0 + j) * 8 + 4);
      acc[0] += xs * g0.x; acc[1] += xs * g0.y; acc[2] += xs * g0.z; acc[3] += xs * g0.w;
      acc[4] += xs * g1.x; acc[5] += xs * g1.y; acc[6] += xs * g1.z; acc[7] += xs * g1.w;
    }
  }
#pragma unroll
  for (int m = 1; m < 64; m <<= 1) {
#pragma unroll
    for (int e = 0; e < 8; e++) acc[e] += __shfl_xor(acc[e], m, 64);
  }
  if (lane == 0) {
    float mx = acc[0];
#pragma unroll
    for (int e = 1; e < 8; e++) mx = fmaxf(mx, acc[e]);
    float p[8]; float s = 0.f;
#pragma unroll
    for (int e = 0; e < 8; e++) { p[e] = __expf(acc[e] - mx); s += p[e]; }
    float inv = 1.0f / s;
    int e0 = 0; float b0 = acc[0];
#pragma unroll
    for (int e = 1; e < 8; e++) if (acc[e] > b0) { b0 = acc[e]; e0 = e; }
    int e1 = -1; float b1 = -1e30f;
#pragma unroll
    for (int e = 0; e < 8; e++) if (e != e0 && acc[e] > b1) { b1 = acc[e]; e1 = e; }
#pragma unroll
    for (int e = 0; e < 8; e++) logits_out[(size_t)t * 8 + e] = acc[e];
    te[t * 2] = e0; te[t * 2 + 1] = e1;
    tw[t * 2] = p[e0] * inv; tw[t * 2 + 1] = p[e1] * inv;
    atomicAdd(&counts[e0], 1);
    atomicAdd(&counts[e1], 1);
  }
}

// ---------------- tiny prefix sum over 8 experts ----------------
__global__ void scan_kernel(const int* __restrict__ counts, int* __restrict__ offs,
                            int* __restrict__ cursor) {
  if (threadIdx.x == 0) {
    int a = 0;
    for (int e = 0; e < E_NUM; e++) { offs[e] = a; a += counts[e]; cursor[e] = 0; }
    offs[E_NUM] = a;
  }
}

// ---------------- scatter tokens into per-expert compact lists ----------------
__global__ void scatter_kernel(const int* __restrict__ te, const float* __restrict__ tw,
                               const int* __restrict__ offs, int* __restrict__ cursor,
                               int* __restrict__ token_list, float* __restrict__ weight_list) {
  int t = blockIdx.x * blockDim.x + threadIdx.x;
  if (t >= T_TOK) return;
#pragma unroll
  for (int k = 0; k < 2; k++) {
    int e = te[t * 2 + k];
    int pos = atomicAdd(&cursor[e], 1);
    token_list[offs[e] + pos] = t;
    weight_list[offs[e] + pos] = tw[t * 2 + k];
  }
}

// ---------------- GEMM1: mid = silu(Xe @ Wg) * (Xe @ Wu)  [bf16 MFMA] ----------------
#define BK 32
#define LDK 40  // BK + 8 pad: 80 B row stride -> 2-way LDS aliasing (free), 16 B aligned

__global__ __launch_bounds__(256, 2) void gemm1_kernel(
    const u16* __restrict__ xb, const u16* __restrict__ wgt, const u16* __restrict__ wut,
    const int* __restrict__ token_list, const int* __restrict__ offs, u16* __restrict__ mid) {
  const int e = blockIdx.z;
  const int off = offs[e];
  const int count = offs[e + 1] - off;
  const int row0 = blockIdx.y * 128;
  if (row0 >= count) return;
  const int n0 = blockIdx.x * 128;

  __shared__ __align__(16) u16 As[128 * LDK];
  __shared__ __align__(16) u16 Bg[128 * LDK];
  __shared__ __align__(16) u16 Bu[128 * LDK];

  const int tid = threadIdx.x;
  const int wave = tid >> 6, lane = tid & 63;
  const int wm = (wave >> 1) * 64, wn = (wave & 1) * 64;
  const int quad = lane >> 4, lr = lane & 15;

  f32x4 accg[4][4], accu[4][4];
  f32x4 z = {0.f, 0.f, 0.f, 0.f};
#pragma unroll
  for (int i = 0; i < 4; i++)
#pragma unroll
    for (int j = 0; j < 4; j++) { accg[i][j] = z; accu[i][j] = z; }

  int srow[2], skc[2]; long sa[2]; bool svalid[2];
#pragma unroll
  for (int i = 0; i < 2; i++) {
    int ci = tid + i * 256;
    srow[i] = ci >> 2; skc[i] = ci & 3;
    int row = row0 + srow[i];
    svalid[i] = row < count;
    int tok = svalid[i] ? token_list[off + row] : 0;
    sa[i] = (long)tok * H_DIM + skc[i] * 8;
  }
  const u16* wgb = wgt + (size_t)e * I_DIM * H_DIM;
  const u16* wub = wut + (size_t)e * I_DIM * H_DIM;

  for (int kt = 0; kt < H_DIM / BK; kt++) {
    const int k0 = kt * BK;
#pragma unroll
    for (int i = 0; i < 2; i++) {
      uint4 av = make_uint4(0, 0, 0, 0);
      if (svalid[i]) av = *(const uint4*)(xb + sa[i] + k0);
      *(uint4*)(&As[srow[i] * LDK + skc[i] * 8]) = av;
      size_t bo = (size_t)(n0 + srow[i]) * H_DIM + k0 + skc[i] * 8;
      *(uint4*)(&Bg[srow[i] * LDK + skc[i] * 8]) = *(const uint4*)(wgb + bo);
      *(uint4*)(&Bu[srow[i] * LDK + skc[i] * 8]) = *(const uint4*)(wub + bo);
    }
    __syncthreads();
    short8 af[4];
#pragma unroll
    for (int im = 0; im < 4; im++)
      af[im] = *(const short8*)(&As[(wm + im * 16 + lr) * LDK + quad * 8]);
#pragma unroll
    for (int in = 0; in < 4; in++) {
      short8 bg = *(const short8*)(&Bg[(wn + in * 16 + lr) * LDK + quad * 8]);
      short8 bu = *(const short8*)(&Bu[(wn + in * 16 + lr) * LDK + quad * 8]);
#pragma unroll
      for (int im = 0; im < 4; im++) {
        accg[im][in] = __builtin_amdgcn_mfma_f32_16x16x32_bf16(af[im], bg, accg[im][in], 0, 0, 0);
        accu[im][in] = __builtin_amdgcn_mfma_f32_16x16x32_bf16(af[im], bu, accu[im][in], 0, 0, 0);
      }
    }
    __syncthreads();
  }

#pragma unroll
  for (int im = 0; im < 4; im++) {
#pragma unroll
    for (int r = 0; r < 4; r++) {
      int row = row0 + wm + im * 16 + quad * 4 + r;
      if (row < count) {
        u16* mrow = mid + (size_t)(off + row) * I_DIM + n0 + wn;
#pragma unroll
        for (int in = 0; in < 4; in++) {
          float g = accg[im][in][r];
          float u = accu[im][in][r];
          float sv = g / (1.0f + __expf(-g)) * u;  // silu(g) * u
          mrow[in * 16 + lr] = f2bf(sv);
        }
      }
    }
  }
}

// ---------------- GEMM2: out[t] += w * (mid_row @ Wd)  [bf16 MFMA + atomic scatter] ----------------
__global__ __launch_bounds__(256, 2) void gemm2_kernel(
    const u16* __restrict__ mid, const u16* __restrict__ wdt,
    const int* __restrict__ token_list, const float* __restrict__ weight_list,
    const int* __restrict__ offs, float* __restrict__ out) {
  const int e = blockIdx.z;
  const int off = offs[e];
  const int count = offs[e + 1] - off;
  const int row0 = blockIdx.y * 128;
  if (row0 >= count) return;
  const int n0 = blockIdx.x * 128;

  __shared__ __align__(16) u16 As[128 * LDK];
  __shared__ __align__(16) u16 Bs[128 * LDK];

  const int tid = threadIdx.x;
  const int wave = tid >> 6, lane = tid & 63;
  const int wm = (wave >> 1) * 64, wn = (wave & 1) * 64;
  const int quad = lane >> 4, lr = lane & 15;

  f32x4 acc[4][4];
  f32x4 z = {0.f, 0.f, 0.f, 0.f};
#pragma unroll
  for (int i = 0; i < 4; i++)
#pragma unroll
    for (int j = 0; j < 4; j++) acc[i][j] = z;

  int srow[2], skc[2]; bool svalid[2];
#pragma unroll
  for (int i = 0; i < 2; i++) {
    int ci = tid + i * 256;
    srow[i] = ci >> 2; skc[i] = ci & 3;
    svalid[i] = (row0 + srow[i]) < count;
  }
  const u16* wdb = wdt + (size_t)e * H_DIM * I_DIM;

  for (int kt = 0; kt < I_DIM / BK; kt++) {
    const int k0 = kt * BK;
#pragma unroll
    for (int i = 0; i < 2; i++) {
      uint4 av = make_uint4(0, 0, 0, 0);
      if (svalid[i])
        av = *(const uint4*)(mid + (size_t)(off + row0 + srow[i]) * I_DIM + k0 + skc[i] * 8);
      *(uint4*)(&As[srow[i] * LDK + skc[i] * 8]) = av;
      *(uint4*)(&Bs[srow[i] * LDK + skc[i] * 8]) =
          *(const uint4*)(wdb + (size_t)(n0 + srow[i]) * I_DIM + k0 + skc[i] * 8);
    }
    __syncthreads();
    short8 af[4];
#pragma unroll
    for (int im = 0; im < 4; im++)
      af[im] = *(const short8*)(&As[(wm + im * 16 + lr) * LDK + quad * 8]);
#pragma unroll
    for (int in = 0; in < 4; in++) {
      short8 bf = *(const short8*)(&Bs[(wn + in * 16 + lr) * LDK + quad * 8]);
#pragma unroll
      for (int im = 0; im < 4; im++)
        acc[im][in] = __builtin_amdgcn_mfma_f32_16x16x32_bf16(af[im], bf, acc[im][in], 0, 0, 0);
    }
    __syncthreads();
  }

#pragma unroll
  for (int im = 0; im < 4; im++) {
#pragma unroll
    for (int r = 0; r < 4; r++) {
      int row = row0 + wm + im * 16 + quad * 4 + r;
      if (row < count) {
        int t = token_list[off + row];
        float wgt_ = weight_list[off + row];
        float* orow = out + (size_t)t * H_DIM + n0 + wn;
#pragma unroll
        for (int in = 0; in < 4; in++)
          atomicAdd(&orow[in * 16 + lr], wgt_ * acc[im][in][r]);
      }
    }
  }
}

// ---------------- launch ----------------
extern "C" void kernel_launch(void* const* d_in, const int* in_sizes, int n_in,
                              void* d_out, int out_size, void* d_ws, size_t ws_size,
                              hipStream_t stream) {
  const float* x  = (const float*)d_in[0];   // [T, H]
  const float* gw = (const float*)d_in[1];   // [H, E]
  const float* Wg = (const float*)d_in[2];   // [E, H, I]
  const float* Wu = (const float*)d_in[3];   // [E, H, I]
  const float* Wd = (const float*)d_in[4];   // [E, I, H]
  float* out = (float*)d_out;                          // [T, H]
  float* out_logits = out + (size_t)T_TOK * H_DIM;     // [T, E]

  char* w = (char*)d_ws;
  size_t o = 0;
  auto take = [&](size_t bytes) { char* p = w + o; o += (bytes + 255) & ~(size_t)255; return p; };
  int*   counts      = (int*)take(E_NUM * 4);
  int*   offs        = (int*)take((E_NUM + 1) * 4);
  int*   cursor      = (int*)take(E_NUM * 4);
  int*   te          = (int*)take((size_t)T_TOK * 2 * 4);
  float* tw          = (float*)take((size_t)T_TOK * 2 * 4);
  int*   token_list  = (int*)take((size_t)T_TOK * 2 * 4);
  float* weight_list = (float*)take((size_t)T_TOK * 2 * 4);
  u16*   xb          = (u16*)take((size_t)T_TOK * H_DIM * 2);
  u16*   wgt         = (u16*)take((size_t)E_NUM * H_DIM * I_DIM * 2);  // [E][I][H] bf16
  u16*   wut         = (u16*)take((size_t)E_NUM * H_DIM * I_DIM * 2);  // [E][I][H] bf16
  u16*   wdt         = (u16*)take((size_t)E_NUM * H_DIM * I_DIM * 2);  // [E][H][I] bf16
  u16*   mid         = (u16*)take((size_t)T_TOK * 2 * I_DIM * 2);      // [T*2][I] bf16
  (void)in_sizes; (void)n_in; (void)out_size; (void)ws_size;

  zero_kernel<<<256, 256, 0, stream>>>(out, T_TOK * H_DIM / 4, counts);
  cvt_x_kernel<<<1024, 256, 0, stream>>>(x, xb, T_TOK * H_DIM / 4);
  tconv_kernel<<<dim3(I_DIM / 32, H_DIM / 32, E_NUM), dim3(32, 8), 0, stream>>>(Wg, wgt, H_DIM, I_DIM);
  tconv_kernel<<<dim3(I_DIM / 32, H_DIM / 32, E_NUM), dim3(32, 8), 0, stream>>>(Wu, wut, H_DIM, I_DIM);
  tconv_kernel<<<dim3(H_DIM / 32, I_DIM / 32, E_NUM), dim3(32, 8), 0, stream>>>(Wd, wdt, I_DIM, H_DIM);
  router_kernel<<<T_TOK / 4, 256, 0, stream>>>(x, gw, out_logits, counts, te, tw);
  scan_kernel<<<1, 64, 0, stream>>>(counts, offs, cursor);
  scatter_kernel<<<T_TOK / 256, 256, 0, stream>>>(te, tw, offs, cursor, token_list, weight_list);
  gemm1_kernel<<<dim3(I_DIM / 128, 32, E_NUM), 256, 0, stream>>>(xb, wgt, wut, token_list, offs, mid);
  gemm2_kernel<<<dim3(H_DIM / 128, 32, E_NUM), 256, 0, stream>>>(mid, wdt, token_list, weight_list, offs, out);
}

// Round 2
// 600.466 us; speedup vs baseline: 1.0565x; 1.0565x over previous
//
#include <hip/hip_runtime.h>
#include <stdint.h>
#include <math.h>

#define T_TOK 4096
#define H_DIM 1024
#define I_DIM 2048
#define E_NUM 8
#define PMAX (T_TOK * 2 + E_NUM * 128)  // padded dispatch rows upper bound

typedef __attribute__((ext_vector_type(8))) short short8;
typedef __attribute__((ext_vector_type(4))) float f32x4;
typedef unsigned short u16;
typedef unsigned int u32;

__device__ __forceinline__ u16 f2bf(float f) {
  union { float f; u32 u; } v; v.f = f;
  u32 r = v.u + 0x7fffu + ((v.u >> 16) & 1u);  // round-to-nearest-even
  return (u16)(r >> 16);
}

// async global->LDS DMA, 16 B per lane. LDS dest semantics: wave-uniform base
// + lane*16 (m104/m108). We pass the per-thread address; lane 0's address IS
// the wave base and our layout is lane-sequential, so either readfirstlane or
// per-lane semantics give the intended placement.
__device__ __forceinline__ void async_ld16(const u16* g, u16* l) {
  __builtin_amdgcn_global_load_lds(
      (const __attribute__((address_space(1))) void*)g,
      (__attribute__((address_space(3))) void*)l, 16, 0, 0);
}

// ---------------- zero init: out, counts, token_list, weight_list ----------------
__global__ void zero_kernel(float* __restrict__ out, int n4, int* __restrict__ counts,
                            int* __restrict__ token_list, float* __restrict__ weight_list) {
  int i = blockIdx.x * blockDim.x + threadIdx.x;
  int stride = gridDim.x * blockDim.x;
  float4 z = make_float4(0.f, 0.f, 0.f, 0.f);
  for (int j = i; j < n4; j += stride) ((float4*)out)[j] = z;
  for (int j = i; j < PMAX; j += stride) { token_list[j] = 0; weight_list[j] = 0.f; }
  if (blockIdx.x == 0 && threadIdx.x < E_NUM) counts[threadIdx.x] = 0;
}

// ---------------- x fp32 -> bf16 ----------------
__global__ void cvt_x_kernel(const float* __restrict__ x, u16* __restrict__ xb, int n4) {
  int i = blockIdx.x * blockDim.x + threadIdx.x;
  int stride = gridDim.x * blockDim.x;
  for (int j = i; j < n4; j += stride) {
    float4 v = ((const float4*)x)[j];
    ushort4 o;
    o.x = f2bf(v.x); o.y = f2bf(v.y); o.z = f2bf(v.z); o.w = f2bf(v.w);
    ((ushort4*)xb)[j] = o;
  }
}

// ---------------- transpose + convert: src [R][C] fp32 -> dst [C][R] bf16, batched over E ----------------
__global__ void tconv_kernel(const float* __restrict__ src, u16* __restrict__ dst, int R, int C) {
  __shared__ float tile[32][33];
  const float* s = src + (size_t)blockIdx.z * R * C;
  u16* d = dst + (size_t)blockIdx.z * R * C;
  int c0 = blockIdx.x * 32, r0 = blockIdx.y * 32;
  for (int i = threadIdx.y; i < 32; i += 8)
    tile[i][threadIdx.x] = s[(size_t)(r0 + i) * C + c0 + threadIdx.x];
  __syncthreads();
  for (int i = threadIdx.y; i < 32; i += 8)
    d[(size_t)(c0 + i) * R + r0 + threadIdx.x] = f2bf(tile[threadIdx.x][i]);
}

// ---------------- router: logits, softmax, top-2 (one wave per token) ----------------
__global__ void router_kernel(const float* __restrict__ x, const float* __restrict__ gw,
                              float* __restrict__ logits_out, int* __restrict__ counts,
                              int* __restrict__ te, float* __restrict__ tw) {
  const int wave = threadIdx.x >> 6, lane = threadIdx.x & 63;
  const int t = blockIdx.x * 4 + wave;
  const float* xr = x + (size_t)t * H_DIM;
  float acc[8];
#pragma unroll
  for (int e = 0; e < 8; e++) acc[e] = 0.f;
#pragma unroll
  for (int it = 0; it < 4; it++) {
    int h0 = it * 256 + lane * 4;
    float4 xv = *(const float4*)(xr + h0);
#pragma unroll
    for (int j = 0; j < 4; j++) {
      float xs = (j == 0) ? xv.x : (j == 1) ? xv.y : (j == 2) ? xv.z : xv.w;
      float4 g0 = *(const float4*)(gw + (size_t)(h0 + j) * 8);
      float4 g1 = *(const float4*)(gw + (size_t)(h0 + j) * 8 + 4);
      acc[0] += xs * g0.x; acc[1] += xs * g0.y; acc[2] += xs * g0.z; acc[3] += xs * g0.w;
      acc[4] += xs * g1.x; acc[5] += xs * g1.y; acc[6] += xs * g1.z; acc[7] += xs * g1.w;
    }
  }
#pragma unroll
  for (int m = 1; m < 64; m <<= 1) {
#pragma unroll
    for (int e = 0; e < 8; e++) acc[e] += __shfl_xor(acc[e], m, 64);
  }
  if (lane == 0) {
    float mx = acc[0];
#pragma unroll
    for (int e = 1; e < 8; e++) mx = fmaxf(mx, acc[e]);
    float p[8]; float s = 0.f;
#pragma unroll
    for (int e = 0; e < 8; e++) { p[e] = __expf(acc[e] - mx); s += p[e]; }
    float inv = 1.0f / s;
    int e0 = 0; float b0 = acc[0];
#pragma unroll
    for (int e = 1; e < 8; e++) if (acc[e] > b0) { b0 = acc[e]; e0 = e; }
    int e1 = -1; float b1 = -1e30f;
#pragma unroll
    for (int e = 0; e < 8; e++) if (e != e0 && acc[e] > b1) { b1 = acc[e]; e1 = e; }
#pragma unroll
    for (int e = 0; e < 8; e++) logits_out[(size_t)t * 8 + e] = acc[e];
    te[t * 2] = e0; te[t * 2 + 1] = e1;
    tw[t * 2] = p[e0] * inv; tw[t * 2 + 1] = p[e1] * inv;
    atomicAdd(&counts[e0], 1);
    atomicAdd(&counts[e1], 1);
  }
}

// ---------------- prefix sum over 8 experts, offsets padded to 128 ----------------
__global__ void scan_kernel(const int* __restrict__ counts, int* __restrict__ offs,
                            int* __restrict__ cursor) {
  if (threadIdx.x == 0) {
    int a = 0;
    for (int e = 0; e < E_NUM; e++) {
      offs[e] = a;
      a += (counts[e] + 127) & ~127;
      cursor[e] = 0;
    }
    offs[E_NUM] = a;
  }
}

// ---------------- scatter tokens into per-expert compact lists ----------------
__global__ void scatter_kernel(const int* __restrict__ te, const float* __restrict__ tw,
                               const int* __restrict__ offs, int* __restrict__ cursor,
                               int* __restrict__ token_list, float* __restrict__ weight_list) {
  int t = blockIdx.x * blockDim.x + threadIdx.x;
  if (t >= T_TOK) return;
#pragma unroll
  for (int k = 0; k < 2; k++) {
    int e = te[t * 2 + k];
    int pos = atomicAdd(&cursor[e], 1);
    token_list[offs[e] + pos] = t;
    weight_list[offs[e] + pos] = tw[t * 2 + k];
  }
}

// ---------------- GEMM1: mid = silu(Xe @ Wg) * (Xe @ Wu)  [bf16 MFMA, async LDS staging] ----------------
#define BK 32

__global__ __launch_bounds__(256, 2) void gemm1_kernel(
    const u16* __restrict__ xb, const u16* __restrict__ wgt, const u16* __restrict__ wut,
    const int* __restrict__ token_list, const int* __restrict__ offs, u16* __restrict__ mid) {
  const int e = blockIdx.z;
  const int off = offs[e];
  const int pcount = offs[e + 1] - off;  // padded to 128
  const int row0 = blockIdx.y * 128;
  if (row0 >= pcount) return;
  const int n0 = blockIdx.x * 128;

  __shared__ __align__(16) u16 As[128 * BK];
  __shared__ __align__(16) u16 Bg[128 * BK];
  __shared__ __align__(16) u16 Bu[128 * BK];

  const int tid = threadIdx.x;
  const int wave = tid >> 6, lane = tid & 63;
  const int wm = (wave >> 1) * 64, wn = (wave & 1) * 64;
  const int quad = lane >> 4, lr = lane & 15;

  f32x4 accg[4][4], accu[4][4];
  f32x4 z = {0.f, 0.f, 0.f, 0.f};
#pragma unroll
  for (int i = 0; i < 4; i++)
#pragma unroll
    for (int j = 0; j < 4; j++) { accg[i][j] = z; accu[i][j] = z; }

  const u16* wgb = wgt + (size_t)e * I_DIM * H_DIM;
  const u16* wub = wut + (size_t)e * I_DIM * H_DIM;

  // staging assignment: chunk c = tid + 256*i covers (row=c>>2, kc=c&3), 16 B each
  const u16* ga[2]; const u16* gg[2]; const u16* gu[2];
  u16 *la[2], *lg[2], *lu[2];
#pragma unroll
  for (int i = 0; i < 2; i++) {
    int c = tid + 256 * i;
    int row = c >> 2, kc = c & 3;
    int tok = token_list[off + row0 + row];  // padded rows -> token 0 (harmless)
    ga[i] = xb + (size_t)tok * H_DIM + kc * 8;
    gg[i] = wgb + (size_t)(n0 + row) * H_DIM + kc * 8;
    gu[i] = wub + (size_t)(n0 + row) * H_DIM + kc * 8;
    la[i] = &As[c * 8]; lg[i] = &Bg[c * 8]; lu[i] = &Bu[c * 8];
  }

  for (int kt = 0; kt < H_DIM / BK; kt++) {
    const int k0 = kt * BK;
#pragma unroll
    for (int i = 0; i < 2; i++) {
      async_ld16(ga[i] + k0, la[i]);
      async_ld16(gg[i] + k0, lg[i]);
      async_ld16(gu[i] + k0, lu[i]);
    }
    __syncthreads();
    short8 af[4];
#pragma unroll
    for (int im = 0; im < 4; im++)
      af[im] = *(const short8*)(&As[(wm + im * 16 + lr) * BK + quad * 8]);
#pragma unroll
    for (int in = 0; in < 4; in++) {
      short8 bg = *(const short8*)(&Bg[(wn + in * 16 + lr) * BK + quad * 8]);
      short8 bu = *(const short8*)(&Bu[(wn + in * 16 + lr) * BK + quad * 8]);
#pragma unroll
      for (int im = 0; im < 4; im++) {
        accg[im][in] = __builtin_amdgcn_mfma_f32_16x16x32_bf16(af[im], bg, accg[im][in], 0, 0, 0);
        accu[im][in] = __builtin_amdgcn_mfma_f32_16x16x32_bf16(af[im], bu, accu[im][in], 0, 0, 0);
      }
    }
    __syncthreads();
  }

#pragma unroll
  for (int im = 0; im < 4; im++) {
#pragma unroll
    for (int r = 0; r < 4; r++) {
      int row = row0 + wm + im * 16 + quad * 4 + r;  // always < pcount
      u16* mrow = mid + (size_t)(off + row) * I_DIM + n0 + wn;
#pragma unroll
      for (int in = 0; in < 4; in++) {
        float g = accg[im][in][r];
        float u = accu[im][in][r];
        float sv = g / (1.0f + __expf(-g)) * u;  // silu(g) * u
        mrow[in * 16 + lr] = f2bf(sv);
      }
    }
  }
}

// ---------------- GEMM2: out[t] += w * (mid_row @ Wd)  [bf16 MFMA + atomic scatter] ----------------
__global__ __launch_bounds__(256, 2) void gemm2_kernel(
    const u16* __restrict__ mid, const u16* __restrict__ wdt,
    const int* __restrict__ token_list, const float* __restrict__ weight_list,
    const int* __restrict__ offs, const int* __restrict__ counts, float* __restrict__ out) {
  const int e = blockIdx.z;
  const int off = offs[e];
  const int pcount = offs[e + 1] - off;
  const int count = counts[e];  // real count (epilogue guard: no atomic pileup on token 0)
  const int row0 = blockIdx.y * 128;
  if (row0 >= pcount) return;
  const int n0 = blockIdx.x * 128;

  __shared__ __align__(16) u16 As[128 * BK];
  __shared__ __align__(16) u16 Bs[128 * BK];

  const int tid = threadIdx.x;
  const int wave = tid >> 6, lane = tid & 63;
  const int wm = (wave >> 1) * 64, wn = (wave & 1) * 64;
  const int quad = lane >> 4, lr = lane & 15;

  f32x4 acc[4][4];
  f32x4 z = {0.f, 0.f, 0.f, 0.f};
#pragma unroll
  for (int i = 0; i < 4; i++)
#pragma unroll
    for (int j = 0; j < 4; j++) acc[i][j] = z;

  const u16* wdb = wdt + (size_t)e * H_DIM * I_DIM;

  const u16* ga[2]; const u16* gb[2];
  u16 *la[2], *lb[2];
#pragma unroll
  for (int i = 0; i < 2; i++) {
    int c = tid + 256 * i;
    int row = c >> 2, kc = c & 3;
    ga[i] = mid + (size_t)(off + row0 + row) * I_DIM + kc * 8;
    gb[i] = wdb + (size_t)(n0 + row) * I_DIM + kc * 8;
    la[i] = &As[c * 8]; lb[i] = &Bs[c * 8];
  }

  for (int kt = 0; kt < I_DIM / BK; kt++) {
    const int k0 = kt * BK;
#pragma unroll
    for (int i = 0; i < 2; i++) {
      async_ld16(ga[i] + k0, la[i]);
      async_ld16(gb[i] + k0, lb[i]);
    }
    __syncthreads();
    short8 af[4];
#pragma unroll
    for (int im = 0; im < 4; im++)
      af[im] = *(const short8*)(&As[(wm + im * 16 + lr) * BK + quad * 8]);
#pragma unroll
    for (int in = 0; in < 4; in++) {
      short8 bf = *(const short8*)(&Bs[(wn + in * 16 + lr) * BK + quad * 8]);
#pragma unroll
      for (int im = 0; im < 4; im++)
        acc[im][in] = __builtin_amdgcn_mfma_f32_16x16x32_bf16(af[im], bf, acc[im][in], 0, 0, 0);
    }
    __syncthreads();
  }

#pragma unroll
  for (int im = 0; im < 4; im++) {
#pragma unroll
    for (int r = 0; r < 4; r++) {
      int row = row0 + wm + im * 16 + quad * 4 + r;
      if (row < count) {
        int t = token_list[off + row];
        float wgt_ = weight_list[off + row];
        float* orow = out + (size_t)t * H_DIM + n0 + wn;
#pragma unroll
        for (int in = 0; in < 4; in++)
          atomicAdd(&orow[in * 16 + lr], wgt_ * acc[im][in][r]);
      }
    }
  }
}

// ---------------- launch ----------------
extern "C" void kernel_launch(void* const* d_in, const int* in_sizes, int n_in,
                              void* d_out, int out_size, void* d_ws, size_t ws_size,
                              hipStream_t stream) {
  const float* x  = (const float*)d_in[0];   // [T, H]
  const float* gw = (const float*)d_in[1];   // [H, E]
  const float* Wg = (const float*)d_in[2];   // [E, H, I]
  const float* Wu = (const float*)d_in[3];   // [E, H, I]
  const float* Wd = (const float*)d_in[4];   // [E, I, H]
  float* out = (float*)d_out;                          // [T, H]
  float* out_logits = out + (size_t)T_TOK * H_DIM;     // [T, E]

  char* w = (char*)d_ws;
  size_t o = 0;
  auto take = [&](size_t bytes) { char* p = w + o; o += (bytes + 255) & ~(size_t)255; return p; };
  int*   counts      = (int*)take(E_NUM * 4);
  int*   offs        = (int*)take((E_NUM + 1) * 4);
  int*   cursor      = (int*)take(E_NUM * 4);
  int*   te          = (int*)take((size_t)T_TOK * 2 * 4);
  float* tw          = (float*)take((size_t)T_TOK * 2 * 4);
  int*   token_list  = (int*)take((size_t)PMAX * 4);
  float* weight_list = (float*)take((size_t)PMAX * 4);
  u16*   xb          = (u16*)take((size_t)T_TOK * H_DIM * 2);
  u16*   wgt         = (u16*)take((size_t)E_NUM * H_DIM * I_DIM * 2);  // [E][I][H] bf16
  u16*   wut         = (u16*)take((size_t)E_NUM * H_DIM * I_DIM * 2);  // [E][I][H] bf16
  u16*   wdt         = (u16*)take((size_t)E_NUM * H_DIM * I_DIM * 2);  // [E][H][I] bf16
  u16*   mid         = (u16*)take((size_t)PMAX * I_DIM * 2);           // [PMAX][I] bf16
  (void)in_sizes; (void)n_in; (void)out_size; (void)ws_size;

  zero_kernel<<<256, 256, 0, stream>>>(out, T_TOK * H_DIM / 4, counts, token_list, weight_list);
  cvt_x_kernel<<<1024, 256, 0, stream>>>(x, xb, T_TOK * H_DIM / 4);
  tconv_kernel<<<dim3(I_DIM / 32, H_DIM / 32, E_NUM), dim3(32, 8), 0, stream>>>(Wg, wgt, H_DIM, I_DIM);
  tconv_kernel<<<dim3(I_DIM / 32, H_DIM / 32, E_NUM), dim3(32, 8), 0, stream>>>(Wu, wut, H_DIM, I_DIM);
  tconv_kernel<<<dim3(H_DIM / 32, I_DIM / 32, E_NUM), dim3(32, 8), 0, stream>>>(Wd, wdt, I_DIM, H_DIM);
  router_kernel<<<T_TOK / 4, 256, 0, stream>>>(x, gw, out_logits, counts, te, tw);
  scan_kernel<<<1, 64, 0, stream>>>(counts, offs, cursor);
  scatter_kernel<<<T_TOK / 256, 256, 0, stream>>>(te, tw, offs, cursor, token_list, weight_list);
  gemm1_kernel<<<dim3(I_DIM / 128, PMAX / 128, E_NUM), 256, 0, stream>>>(xb, wgt, wut, token_list, offs, mid);
  gemm2_kernel<<<dim3(H_DIM / 128, PMAX / 128, E_NUM), 256, 0, stream>>>(mid, wdt, token_list, weight_list, offs, counts, out);
}

// Round 3
// 572.369 us; speedup vs baseline: 1.1083x; 1.0491x over previous
//
#include <hip/hip_runtime.h>
#include <stdint.h>
#include <math.h>

#define T_TOK 4096
#define H_DIM 1024
#define I_DIM 2048
#define E_NUM 8
#define PMAX (T_TOK * 2 + E_NUM * 128)  // padded dispatch rows upper bound

typedef __attribute__((ext_vector_type(8))) short short8;
typedef __attribute__((ext_vector_type(4))) float f32x4;
typedef unsigned short u16;
typedef unsigned int u32;

__device__ __forceinline__ u16 f2bf(float f) {
  union { float f; u32 u; } v; v.f = f;
  u32 r = v.u + 0x7fffu + ((v.u >> 16) & 1u);  // round-to-nearest-even
  return (u16)(r >> 16);
}

// async global->LDS DMA, 16 B per lane (m97 pattern; dest = wave base + lane*16)
__device__ __forceinline__ void async_ld16(const u16* g, u16* l) {
  __builtin_amdgcn_global_load_lds(
      (const __attribute__((address_space(1))) void*)g,
      (__attribute__((address_space(3))) void*)l, 16, 0, 0);
}

// ---------------- prep: zero out, zero lists, convert x -> bf16 ----------------
__global__ void prep_kernel(const float* __restrict__ x, u16* __restrict__ xb,
                            float* __restrict__ out, int n4, int* __restrict__ counts,
                            int* __restrict__ token_list, float* __restrict__ weight_list) {
  int i = blockIdx.x * blockDim.x + threadIdx.x;
  int stride = gridDim.x * blockDim.x;
  float4 z = make_float4(0.f, 0.f, 0.f, 0.f);
  for (int j = i; j < n4; j += stride) {
    ((float4*)out)[j] = z;
    float4 v = ((const float4*)x)[j];
    ushort4 o;
    o.x = f2bf(v.x); o.y = f2bf(v.y); o.z = f2bf(v.z); o.w = f2bf(v.w);
    ((ushort4*)xb)[j] = o;
  }
  for (int j = i; j < PMAX; j += stride) { token_list[j] = 0; weight_list[j] = 0.f; }
  if (blockIdx.x == 0 && threadIdx.x < E_NUM) counts[threadIdx.x] = 0;
}

// ---------------- fused weight transpose+convert, register 4x4 micro-transpose ----------
// z=0: Wg [E][1024][2048] -> [E][2048][1024] bf16
// z=1: Wu same, z=2: Wd [E][2048][1024] -> [E][1024][2048] bf16
// 64x64 tile per block; no LDS. Loads: 16 B/lane row-contiguous (waves tile full
// 64 B lines). Stores: ushort4, 16 lanes r-contiguous -> 128 B segments.
__global__ void wconv_kernel(const float* __restrict__ Wg, const float* __restrict__ Wu,
                             const float* __restrict__ Wd, u16* __restrict__ wgt,
                             u16* __restrict__ wut, u16* __restrict__ wdt) {
  const int zz = blockIdx.z;
  const float* src = (zz == 0) ? Wg : (zz == 1) ? Wu : Wd;
  u16* dst = (zz == 0) ? wgt : (zz == 1) ? wut : wdt;
  const int R = (zz == 2) ? I_DIM : H_DIM;
  const int C = (zz == 2) ? H_DIM : I_DIM;
  const int cpt = C >> 6;                 // 64-col tiles per row band
  const int e = blockIdx.x >> 9;          // 512 tiles per expert
  const int ti = blockIdx.x & 511;
  const int r0 = (ti / cpt) << 6;
  const int c0 = (ti % cpt) << 6;
  const float* s = src + (size_t)e * H_DIM * I_DIM;
  u16* d = dst + (size_t)e * H_DIM * I_DIM;

  const int wave = threadIdx.x >> 6, lane = threadIdx.x & 63;
  const int g = lane >> 4, lq = lane & 15;
  const int c = c0 + wave * 16 + g * 4;   // this thread's 4 cols: c..c+3
  const int r = r0 + lq * 4;              // this thread's 4 rows: r..r+3

  float4 v0 = *(const float4*)(s + (size_t)(r + 0) * C + c);
  float4 v1 = *(const float4*)(s + (size_t)(r + 1) * C + c);
  float4 v2 = *(const float4*)(s + (size_t)(r + 2) * C + c);
  float4 v3 = *(const float4*)(s + (size_t)(r + 3) * C + c);

  ushort4 o;
  o.x = f2bf(v0.x); o.y = f2bf(v1.x); o.z = f2bf(v2.x); o.w = f2bf(v3.x);
  *(ushort4*)(d + (size_t)(c + 0) * R + r) = o;
  o.x = f2bf(v0.y); o.y = f2bf(v1.y); o.z = f2bf(v2.y); o.w = f2bf(v3.y);
  *(ushort4*)(d + (size_t)(c + 1) * R + r) = o;
  o.x = f2bf(v0.z); o.y = f2bf(v1.z); o.z = f2bf(v2.z); o.w = f2bf(v3.z);
  *(ushort4*)(d + (size_t)(c + 2) * R + r) = o;
  o.x = f2bf(v0.w); o.y = f2bf(v1.w); o.z = f2bf(v2.w); o.w = f2bf(v3.w);
  *(ushort4*)(d + (size_t)(c + 3) * R + r) = o;
}

// ---------------- router: logits, softmax, top-2 (one wave per token) ----------------
__global__ void router_kernel(const float* __restrict__ x, const float* __restrict__ gw,
                              float* __restrict__ logits_out, int* __restrict__ counts,
                              int* __restrict__ te, float* __restrict__ tw) {
  const int wave = threadIdx.x >> 6, lane = threadIdx.x & 63;
  const int t = blockIdx.x * 4 + wave;
  const float* xr = x + (size_t)t * H_DIM;
  float acc[8];
#pragma unroll
  for (int e = 0; e < 8; e++) acc[e] = 0.f;
#pragma unroll
  for (int it = 0; it < 4; it++) {
    int h0 = it * 256 + lane * 4;
    float4 xv = *(const float4*)(xr + h0);
#pragma unroll
    for (int j = 0; j < 4; j++) {
      float xs = (j == 0) ? xv.x : (j == 1) ? xv.y : (j == 2) ? xv.z : xv.w;
      float4 g0 = *(const float4*)(gw + (size_t)(h0 + j) * 8);
      float4 g1 = *(const float4*)(gw + (size_t)(h0 + j) * 8 + 4);
      acc[0] += xs * g0.x; acc[1] += xs * g0.y; acc[2] += xs * g0.z; acc[3] += xs * g0.w;
      acc[4] += xs * g1.x; acc[5] += xs * g1.y; acc[6] += xs * g1.z; acc[7] += xs * g1.w;
    }
  }
#pragma unroll
  for (int m = 1; m < 64; m <<= 1) {
#pragma unroll
    for (int e = 0; e < 8; e++) acc[e] += __shfl_xor(acc[e], m, 64);
  }
  if (lane == 0) {
    float mx = acc[0];
#pragma unroll
    for (int e = 1; e < 8; e++) mx = fmaxf(mx, acc[e]);
    float p[8]; float s = 0.f;
#pragma unroll
    for (int e = 0; e < 8; e++) { p[e] = __expf(acc[e] - mx); s += p[e]; }
    float inv = 1.0f / s;
    int e0 = 0; float b0 = acc[0];
#pragma unroll
    for (int e = 1; e < 8; e++) if (acc[e] > b0) { b0 = acc[e]; e0 = e; }
    int e1 = -1; float b1 = -1e30f;
#pragma unroll
    for (int e = 0; e < 8; e++) if (e != e0 && acc[e] > b1) { b1 = acc[e]; e1 = e; }
#pragma unroll
    for (int e = 0; e < 8; e++) logits_out[(size_t)t * 8 + e] = acc[e];
    te[t * 2] = e0; te[t * 2 + 1] = e1;
    tw[t * 2] = p[e0] * inv; tw[t * 2 + 1] = p[e1] * inv;
    atomicAdd(&counts[e0], 1);
    atomicAdd(&counts[e1], 1);
  }
}

// ---------------- prefix sum over 8 experts, offsets padded to 128 ----------------
__global__ void scan_kernel(const int* __restrict__ counts, int* __restrict__ offs,
                            int* __restrict__ cursor) {
  if (threadIdx.x == 0) {
    int a = 0;
    for (int e = 0; e < E_NUM; e++) {
      offs[e] = a;
      a += (counts[e] + 127) & ~127;
      cursor[e] = 0;
    }
    offs[E_NUM] = a;
  }
}

// ---------------- scatter tokens into per-expert compact lists ----------------
__global__ void scatter_kernel(const int* __restrict__ te, const float* __restrict__ tw,
                               const int* __restrict__ offs, int* __restrict__ cursor,
                               int* __restrict__ token_list, float* __restrict__ weight_list) {
  int t = blockIdx.x * blockDim.x + threadIdx.x;
  if (t >= T_TOK) return;
#pragma unroll
  for (int k = 0; k < 2; k++) {
    int e = te[t * 2 + k];
    int pos = atomicAdd(&cursor[e], 1);
    token_list[offs[e] + pos] = t;
    weight_list[offs[e] + pos] = tw[t * 2 + k];
  }
}

// ---------------- GEMM1: mid = silu(Xe @ Wg) * (Xe @ Wu)  [bf16 MFMA, async LDS staging] ----------------
#define BK 32

__global__ __launch_bounds__(256, 2) void gemm1_kernel(
    const u16* __restrict__ xb, const u16* __restrict__ wgt, const u16* __restrict__ wut,
    const int* __restrict__ token_list, const int* __restrict__ offs, u16* __restrict__ mid) {
  const int e = blockIdx.z;
  const int off = offs[e];
  const int pcount = offs[e + 1] - off;  // padded to 128
  const int row0 = blockIdx.y * 128;
  if (row0 >= pcount) return;
  const int n0 = blockIdx.x * 128;

  __shared__ __align__(16) u16 As[128 * BK];
  __shared__ __align__(16) u16 Bg[128 * BK];
  __shared__ __align__(16) u16 Bu[128 * BK];

  const int tid = threadIdx.x;
  const int wave = tid >> 6, lane = tid & 63;
  const int wm = (wave >> 1) * 64, wn = (wave & 1) * 64;
  const int quad = lane >> 4, lr = lane & 15;

  f32x4 accg[4][4], accu[4][4];
  f32x4 z = {0.f, 0.f, 0.f, 0.f};
#pragma unroll
  for (int i = 0; i < 4; i++)
#pragma unroll
    for (int j = 0; j < 4; j++) { accg[i][j] = z; accu[i][j] = z; }

  const u16* wgb = wgt + (size_t)e * I_DIM * H_DIM;
  const u16* wub = wut + (size_t)e * I_DIM * H_DIM;

  // staging assignment: chunk c = tid + 256*i covers (row=c>>2, kc=c&3), 16 B each
  const u16* ga[2]; const u16* gg[2]; const u16* gu[2];
  u16 *la[2], *lg[2], *lu[2];
#pragma unroll
  for (int i = 0; i < 2; i++) {
    int c = tid + 256 * i;
    int row = c >> 2, kc = c & 3;
    int tok = token_list[off + row0 + row];  // padded rows -> token 0 (harmless)
    ga[i] = xb + (size_t)tok * H_DIM + kc * 8;
    gg[i] = wgb + (size_t)(n0 + row) * H_DIM + kc * 8;
    gu[i] = wub + (size_t)(n0 + row) * H_DIM + kc * 8;
    la[i] = &As[c * 8]; lg[i] = &Bg[c * 8]; lu[i] = &Bu[c * 8];
  }

  for (int kt = 0; kt < H_DIM / BK; kt++) {
    const int k0 = kt * BK;
#pragma unroll
    for (int i = 0; i < 2; i++) {
      async_ld16(ga[i] + k0, la[i]);
      async_ld16(gg[i] + k0, lg[i]);
      async_ld16(gu[i] + k0, lu[i]);
    }
    __syncthreads();
    short8 af[4];
#pragma unroll
    for (int im = 0; im < 4; im++)
      af[im] = *(const short8*)(&As[(wm + im * 16 + lr) * BK + quad * 8]);
#pragma unroll
    for (int in = 0; in < 4; in++) {
      short8 bg = *(const short8*)(&Bg[(wn + in * 16 + lr) * BK + quad * 8]);
      short8 bu = *(const short8*)(&Bu[(wn + in * 16 + lr) * BK + quad * 8]);
#pragma unroll
      for (int im = 0; im < 4; im++) {
        accg[im][in] = __builtin_amdgcn_mfma_f32_16x16x32_bf16(af[im], bg, accg[im][in], 0, 0, 0);
        accu[im][in] = __builtin_amdgcn_mfma_f32_16x16x32_bf16(af[im], bu, accu[im][in], 0, 0, 0);
      }
    }
    __syncthreads();
  }

#pragma unroll
  for (int im = 0; im < 4; im++) {
#pragma unroll
    for (int r = 0; r < 4; r++) {
      int row = row0 + wm + im * 16 + quad * 4 + r;  // always < pcount
      u16* mrow = mid + (size_t)(off + row) * I_DIM + n0 + wn;
#pragma unroll
      for (int in = 0; in < 4; in++) {
        float g = accg[im][in][r];
        float u = accu[im][in][r];
        float sv = g / (1.0f + __expf(-g)) * u;  // silu(g) * u
        mrow[in * 16 + lr] = f2bf(sv);
      }
    }
  }
}

// ---------------- GEMM2: out[t] += w * (mid_row @ Wd)  [bf16 MFMA + atomic scatter] ----------------
__global__ __launch_bounds__(256, 2) void gemm2_kernel(
    const u16* __restrict__ mid, const u16* __restrict__ wdt,
    const int* __restrict__ token_list, const float* __restrict__ weight_list,
    const int* __restrict__ offs, const int* __restrict__ counts, float* __restrict__ out) {
  const int e = blockIdx.z;
  const int off = offs[e];
  const int pcount = offs[e + 1] - off;
  const int count = counts[e];  // real count (epilogue guard: no atomic pileup on token 0)
  const int row0 = blockIdx.y * 128;
  if (row0 >= pcount) return;
  const int n0 = blockIdx.x * 128;

  __shared__ __align__(16) u16 As[128 * BK];
  __shared__ __align__(16) u16 Bs[128 * BK];

  const int tid = threadIdx.x;
  const int wave = tid >> 6, lane = tid & 63;
  const int wm = (wave >> 1) * 64, wn = (wave & 1) * 64;
  const int quad = lane >> 4, lr = lane & 15;

  f32x4 acc[4][4];
  f32x4 z = {0.f, 0.f, 0.f, 0.f};
#pragma unroll
  for (int i = 0; i < 4; i++)
#pragma unroll
    for (int j = 0; j < 4; j++) acc[i][j] = z;

  const u16* wdb = wdt + (size_t)e * H_DIM * I_DIM;

  const u16* ga[2]; const u16* gb[2];
  u16 *la[2], *lb[2];
#pragma unroll
  for (int i = 0; i < 2; i++) {
    int c = tid + 256 * i;
    int row = c >> 2, kc = c & 3;
    ga[i] = mid + (size_t)(off + row0 + row) * I_DIM + kc * 8;
    gb[i] = wdb + (size_t)(n0 + row) * I_DIM + kc * 8;
    la[i] = &As[c * 8]; lb[i] = &Bs[c * 8];
  }

  for (int kt = 0; kt < I_DIM / BK; kt++) {
    const int k0 = kt * BK;
#pragma unroll
    for (int i = 0; i < 2; i++) {
      async_ld16(ga[i] + k0, la[i]);
      async_ld16(gb[i] + k0, lb[i]);
    }
    __syncthreads();
    short8 af[4];
#pragma unroll
    for (int im = 0; im < 4; im++)
      af[im] = *(const short8*)(&As[(wm + im * 16 + lr) * BK + quad * 8]);
#pragma unroll
    for (int in = 0; in < 4; in++) {
      short8 bf = *(const short8*)(&Bs[(wn + in * 16 + lr) * BK + quad * 8]);
#pragma unroll
      for (int im = 0; im < 4; im++)
        acc[im][in] = __builtin_amdgcn_mfma_f32_16x16x32_bf16(af[im], bf, acc[im][in], 0, 0, 0);
    }
    __syncthreads();
  }

#pragma unroll
  for (int im = 0; im < 4; im++) {
#pragma unroll
    for (int r = 0; r < 4; r++) {
      int row = row0 + wm + im * 16 + quad * 4 + r;
      if (row < count) {
        int t = token_list[off + row];
        float wgt_ = weight_list[off + row];
        float* orow = out + (size_t)t * H_DIM + n0 + wn;
#pragma unroll
        for (int in = 0; in < 4; in++)
          atomicAdd(&orow[in * 16 + lr], wgt_ * acc[im][in][r]);
      }
    }
  }
}

// ---------------- launch ----------------
extern "C" void kernel_launch(void* const* d_in, const int* in_sizes, int n_in,
                              void* d_out, int out_size, void* d_ws, size_t ws_size,
                              hipStream_t stream) {
  const float* x  = (const float*)d_in[0];   // [T, H]
  const float* gw = (const float*)d_in[1];   // [H, E]
  const float* Wg = (const float*)d_in[2];   // [E, H, I]
  const float* Wu = (const float*)d_in[3];   // [E, H, I]
  const float* Wd = (const float*)d_in[4];   // [E, I, H]
  float* out = (float*)d_out;                          // [T, H]
  float* out_logits = out + (size_t)T_TOK * H_DIM;     // [T, E]

  char* w = (char*)d_ws;
  size_t o = 0;
  auto take = [&](size_t bytes) { char* p = w + o; o += (bytes + 255) & ~(size_t)255; return p; };
  int*   counts      = (int*)take(E_NUM * 4);
  int*   offs        = (int*)take((E_NUM + 1) * 4);
  int*   cursor      = (int*)take(E_NUM * 4);
  int*   te          = (int*)take((size_t)T_TOK * 2 * 4);
  float* tw          = (float*)take((size_t)T_TOK * 2 * 4);
  int*   token_list  = (int*)take((size_t)PMAX * 4);
  float* weight_list = (float*)take((size_t)PMAX * 4);
  u16*   xb          = (u16*)take((size_t)T_TOK * H_DIM * 2);
  u16*   wgt         = (u16*)take((size_t)E_NUM * H_DIM * I_DIM * 2);  // [E][I][H] bf16
  u16*   wut         = (u16*)take((size_t)E_NUM * H_DIM * I_DIM * 2);  // [E][I][H] bf16
  u16*   wdt         = (u16*)take((size_t)E_NUM * H_DIM * I_DIM * 2);  // [E][H][I] bf16
  u16*   mid         = (u16*)take((size_t)PMAX * I_DIM * 2);           // [PMAX][I] bf16
  (void)in_sizes; (void)n_in; (void)out_size; (void)ws_size;

  prep_kernel<<<512, 256, 0, stream>>>(x, xb, out, T_TOK * H_DIM / 4, counts, token_list, weight_list);
  wconv_kernel<<<dim3(E_NUM * 512, 1, 3), 256, 0, stream>>>(Wg, Wu, Wd, wgt, wut, wdt);
  router_kernel<<<T_TOK / 4, 256, 0, stream>>>(x, gw, out_logits, counts, te, tw);
  scan_kernel<<<1, 64, 0, stream>>>(counts, offs, cursor);
  scatter_kernel<<<T_TOK / 256, 256, 0, stream>>>(te, tw, offs, cursor, token_list, weight_list);
  gemm1_kernel<<<dim3(I_DIM / 128, PMAX / 128, E_NUM), 256, 0, stream>>>(xb, wgt, wut, token_list, offs, mid);
  gemm2_kernel<<<dim3(H_DIM / 128, PMAX / 128, E_NUM), 256, 0, stream>>>(mid, wdt, token_list, weight_list, offs, counts, out);
}

// Round 4
// 537.600 us; speedup vs baseline: 1.1800x; 1.0647x over previous
//
#include <hip/hip_runtime.h>
#include <stdint.h>
#include <math.h>

#define T_TOK 4096
#define H_DIM 1024
#define I_DIM 2048
#define E_NUM 8
#define PMAX (T_TOK * 2 + E_NUM * 128)  // 9216 padded dispatch rows upper bound

typedef __attribute__((ext_vector_type(8))) short short8;
typedef __attribute__((ext_vector_type(4))) float f32x4;
typedef unsigned short u16;
typedef unsigned int u32;

__device__ __forceinline__ u16 f2bf(float f) {
  union { float f; u32 u; } v; v.f = f;
  u32 r = v.u + 0x7fffu + ((v.u >> 16) & 1u);  // round-to-nearest-even
  return (u16)(r >> 16);
}
__device__ __forceinline__ float bf2f(u16 a) {
  union { u32 u; float f; } v; v.u = ((u32)a) << 16; return v.f;
}

// async global->LDS DMA, 16 B per lane (m97 pattern; dest = wave base + lane*16)
__device__ __forceinline__ void async_ld16(const u16* g, u16* l) {
  __builtin_amdgcn_global_load_lds(
      (const __attribute__((address_space(1))) void*)g,
      (__attribute__((address_space(3))) void*)l, 16, 0, 0);
}

// ---------------- prep: zero lists/counts, convert x -> bf16 ----------------
__global__ void prep_kernel(const float* __restrict__ x, u16* __restrict__ xb,
                            int n4, int* __restrict__ counts, int* __restrict__ token_list) {
  int i = blockIdx.x * blockDim.x + threadIdx.x;
  int stride = gridDim.x * blockDim.x;
  for (int j = i; j < n4; j += stride) {
    float4 v = ((const float4*)x)[j];
    ushort4 o;
    o.x = f2bf(v.x); o.y = f2bf(v.y); o.z = f2bf(v.z); o.w = f2bf(v.w);
    ((ushort4*)xb)[j] = o;
  }
  for (int j = i; j < PMAX; j += stride) token_list[j] = 0;
  if (blockIdx.x == 0 && threadIdx.x < E_NUM) counts[threadIdx.x] = 0;
}

// ---------------- fused weight transpose+convert (register 4x4 micro-transpose) ----------
__global__ void wconv_kernel(const float* __restrict__ Wg, const float* __restrict__ Wu,
                             const float* __restrict__ Wd, u16* __restrict__ wgt,
                             u16* __restrict__ wut, u16* __restrict__ wdt) {
  const int zz = blockIdx.z;
  const float* src = (zz == 0) ? Wg : (zz == 1) ? Wu : Wd;
  u16* dst = (zz == 0) ? wgt : (zz == 1) ? wut : wdt;
  const int R = (zz == 2) ? I_DIM : H_DIM;
  const int C = (zz == 2) ? H_DIM : I_DIM;
  const int cpt = C >> 6;
  const int e = blockIdx.x >> 9;
  const int ti = blockIdx.x & 511;
  const int r0 = (ti / cpt) << 6;
  const int c0 = (ti % cpt) << 6;
  const float* s = src + (size_t)e * H_DIM * I_DIM;
  u16* d = dst + (size_t)e * H_DIM * I_DIM;

  const int wave = threadIdx.x >> 6, lane = threadIdx.x & 63;
  const int g = lane >> 4, lq = lane & 15;
  const int c = c0 + wave * 16 + g * 4;
  const int r = r0 + lq * 4;

  float4 v0 = *(const float4*)(s + (size_t)(r + 0) * C + c);
  float4 v1 = *(const float4*)(s + (size_t)(r + 1) * C + c);
  float4 v2 = *(const float4*)(s + (size_t)(r + 2) * C + c);
  float4 v3 = *(const float4*)(s + (size_t)(r + 3) * C + c);

  ushort4 o;
  o.x = f2bf(v0.x); o.y = f2bf(v1.x); o.z = f2bf(v2.x); o.w = f2bf(v3.x);
  *(ushort4*)(d + (size_t)(c + 0) * R + r) = o;
  o.x = f2bf(v0.y); o.y = f2bf(v1.y); o.z = f2bf(v2.y); o.w = f2bf(v3.y);
  *(ushort4*)(d + (size_t)(c + 1) * R + r) = o;
  o.x = f2bf(v0.z); o.y = f2bf(v1.z); o.z = f2bf(v2.z); o.w = f2bf(v3.z);
  *(ushort4*)(d + (size_t)(c + 2) * R + r) = o;
  o.x = f2bf(v0.w); o.y = f2bf(v1.w); o.z = f2bf(v2.w); o.w = f2bf(v3.w);
  *(ushort4*)(d + (size_t)(c + 3) * R + r) = o;
}

// ---------------- router: logits, softmax, top-2 (one wave per token) ----------------
__global__ void router_kernel(const float* __restrict__ x, const float* __restrict__ gw,
                              float* __restrict__ logits_out, int* __restrict__ counts,
                              int* __restrict__ te, float* __restrict__ tw) {
  const int wave = threadIdx.x >> 6, lane = threadIdx.x & 63;
  const int t = blockIdx.x * 4 + wave;
  const float* xr = x + (size_t)t * H_DIM;
  float acc[8];
#pragma unroll
  for (int e = 0; e < 8; e++) acc[e] = 0.f;
#pragma unroll
  for (int it = 0; it < 4; it++) {
    int h0 = it * 256 + lane * 4;
    float4 xv = *(const float4*)(xr + h0);
#pragma unroll
    for (int j = 0; j < 4; j++) {
      float xs = (j == 0) ? xv.x : (j == 1) ? xv.y : (j == 2) ? xv.z : xv.w;
      float4 g0 = *(const float4*)(gw + (size_t)(h0 + j) * 8);
      float4 g1 = *(const float4*)(gw + (size_t)(h0 + j) * 8 + 4);
      acc[0] += xs * g0.x; acc[1] += xs * g0.y; acc[2] += xs * g0.z; acc[3] += xs * g0.w;
      acc[4] += xs * g1.x; acc[5] += xs * g1.y; acc[6] += xs * g1.z; acc[7] += xs * g1.w;
    }
  }
#pragma unroll
  for (int m = 1; m < 64; m <<= 1) {
#pragma unroll
    for (int e = 0; e < 8; e++) acc[e] += __shfl_xor(acc[e], m, 64);
  }
  if (lane == 0) {
    float mx = acc[0];
#pragma unroll
    for (int e = 1; e < 8; e++) mx = fmaxf(mx, acc[e]);
    float p[8]; float s = 0.f;
#pragma unroll
    for (int e = 0; e < 8; e++) { p[e] = __expf(acc[e] - mx); s += p[e]; }
    float inv = 1.0f / s;
    int e0 = 0; float b0 = acc[0];
#pragma unroll
    for (int e = 1; e < 8; e++) if (acc[e] > b0) { b0 = acc[e]; e0 = e; }
    int e1 = -1; float b1 = -1e30f;
#pragma unroll
    for (int e = 0; e < 8; e++) if (e != e0 && acc[e] > b1) { b1 = acc[e]; e1 = e; }
#pragma unroll
    for (int e = 0; e < 8; e++) logits_out[(size_t)t * 8 + e] = acc[e];
    te[t * 2] = e0; te[t * 2 + 1] = e1;
    tw[t * 2] = p[e0] * inv; tw[t * 2 + 1] = p[e1] * inv;
    atomicAdd(&counts[e0], 1);
    atomicAdd(&counts[e1], 1);
  }
}

// ---------------- prefix sum over 8 experts, offsets padded to 128 ----------------
__global__ void scan_kernel(const int* __restrict__ counts, int* __restrict__ offs,
                            int* __restrict__ cursor) {
  if (threadIdx.x == 0) {
    int a = 0;
    for (int e = 0; e < E_NUM; e++) {
      offs[e] = a;
      a += (counts[e] + 127) & ~127;
      cursor[e] = 0;
    }
    offs[E_NUM] = a;
  }
}

// ---------------- scatter tokens into per-expert compact lists ----------------
__global__ void scatter_kernel(const int* __restrict__ te, const int* __restrict__ offs,
                               int* __restrict__ cursor, int* __restrict__ token_list,
                               int* __restrict__ tpos) {
  int t = blockIdx.x * blockDim.x + threadIdx.x;
  if (t >= T_TOK) return;
#pragma unroll
  for (int k = 0; k < 2; k++) {
    int e = te[t * 2 + k];
    int pos = atomicAdd(&cursor[e], 1);
    token_list[offs[e] + pos] = t;
    tpos[t * 2 + k] = offs[e] + pos;
  }
}

// ---------------- GEMM1: mid = silu(Xe @ Wg) * (Xe @ Wu) ----------------
// 128x128 tile, BK=64, xor-swizzled LDS (swizzle applied on the global side of the DMA)
#define BK1 64

__global__ __launch_bounds__(256, 2) void gemm1_kernel(
    const u16* __restrict__ xb, const u16* __restrict__ wgt, const u16* __restrict__ wut,
    const int* __restrict__ token_list, const int* __restrict__ offs, u16* __restrict__ mid) {
  const int e = blockIdx.z;
  const int off = offs[e];
  const int pcount = offs[e + 1] - off;
  const int row0 = blockIdx.y * 128;
  if (row0 >= pcount) return;
  const int n0 = blockIdx.x * 128;

  __shared__ __align__(16) u16 As[128 * BK1];
  __shared__ __align__(16) u16 Bg[128 * BK1];
  __shared__ __align__(16) u16 Bu[128 * BK1];

  const int tid = threadIdx.x;
  const int wave = tid >> 6, lane = tid & 63;
  const int wm = (wave >> 1) * 64, wn = (wave & 1) * 64;
  const int quad = lane >> 4, lr = lane & 15;
  const int l7 = lr & 7;

  f32x4 accg[4][4], accu[4][4];
  f32x4 z = {0.f, 0.f, 0.f, 0.f};
#pragma unroll
  for (int i = 0; i < 4; i++)
#pragma unroll
    for (int j = 0; j < 4; j++) { accg[i][j] = z; accu[i][j] = z; }

  const u16* wgb = wgt + (size_t)e * I_DIM * H_DIM;
  const u16* wub = wut + (size_t)e * I_DIM * H_DIM;

  // staging: chunk c = tid + 256*i -> (row=c>>3, lds slot kcl=c&7); global chunk kg = kcl^(row&7)
  const u16* ga[4]; const u16* gg[4]; const u16* gu[4];
  u16 *la[4], *lg[4], *lu[4];
#pragma unroll
  for (int i = 0; i < 4; i++) {
    int c = tid + 256 * i;
    int row = c >> 3, kcl = c & 7;
    int kg = kcl ^ (row & 7);
    int tok = token_list[off + row0 + row];  // padded rows -> token 0 (harmless)
    ga[i] = xb + (size_t)tok * H_DIM + kg * 8;
    gg[i] = wgb + (size_t)(n0 + row) * H_DIM + kg * 8;
    gu[i] = wub + (size_t)(n0 + row) * H_DIM + kg * 8;
    la[i] = &As[c * 8]; lg[i] = &Bg[c * 8]; lu[i] = &Bu[c * 8];
  }

  for (int kt = 0; kt < H_DIM / BK1; kt++) {
    const int k0 = kt * BK1;
#pragma unroll
    for (int i = 0; i < 4; i++) {
      async_ld16(ga[i] + k0, la[i]);
      async_ld16(gg[i] + k0, lg[i]);
      async_ld16(gu[i] + k0, lu[i]);
    }
    __syncthreads();
#pragma unroll
    for (int kk = 0; kk < 2; kk++) {
      const int slot = ((kk << 2) + quad) ^ l7;  // physical 16B chunk (row&7 == lr&7 for all frags)
      short8 af[4];
#pragma unroll
      for (int im = 0; im < 4; im++)
        af[im] = *(const short8*)(&As[(wm + im * 16 + lr) * BK1 + slot * 8]);
#pragma unroll
      for (int in = 0; in < 4; in++) {
        short8 bg = *(const short8*)(&Bg[(wn + in * 16 + lr) * BK1 + slot * 8]);
        short8 bu = *(const short8*)(&Bu[(wn + in * 16 + lr) * BK1 + slot * 8]);
#pragma unroll
        for (int im = 0; im < 4; im++) {
          accg[im][in] = __builtin_amdgcn_mfma_f32_16x16x32_bf16(af[im], bg, accg[im][in], 0, 0, 0);
          accu[im][in] = __builtin_amdgcn_mfma_f32_16x16x32_bf16(af[im], bu, accu[im][in], 0, 0, 0);
        }
      }
    }
    __syncthreads();
  }

#pragma unroll
  for (int im = 0; im < 4; im++) {
#pragma unroll
    for (int r = 0; r < 4; r++) {
      int row = row0 + wm + im * 16 + quad * 4 + r;  // always < pcount
      u16* mrow = mid + (size_t)(off + row) * I_DIM + n0 + wn;
#pragma unroll
      for (int in = 0; in < 4; in++) {
        float g = accg[im][in][r];
        float u = accu[im][in][r];
        float sv = g / (1.0f + __expf(-g)) * u;  // silu(g) * u
        mrow[in * 16 + lr] = f2bf(sv);
      }
    }
  }
}

// ---------------- GEMM2: eout = mid @ Wd^T  (dense bf16 store, no atomics) ----------------
__global__ __launch_bounds__(256, 2) void gemm2_kernel(
    const u16* __restrict__ mid, const u16* __restrict__ wdt,
    const int* __restrict__ offs, u16* __restrict__ eout) {
  const int e = blockIdx.z;
  const int off = offs[e];
  const int pcount = offs[e + 1] - off;
  const int row0 = blockIdx.y * 128;
  if (row0 >= pcount) return;
  const int n0 = blockIdx.x * 128;

  __shared__ __align__(16) u16 As[128 * BK1];
  __shared__ __align__(16) u16 Bs[128 * BK1];

  const int tid = threadIdx.x;
  const int wave = tid >> 6, lane = tid & 63;
  const int wm = (wave >> 1) * 64, wn = (wave & 1) * 64;
  const int quad = lane >> 4, lr = lane & 15;
  const int l7 = lr & 7;

  f32x4 acc[4][4];
  f32x4 z = {0.f, 0.f, 0.f, 0.f};
#pragma unroll
  for (int i = 0; i < 4; i++)
#pragma unroll
    for (int j = 0; j < 4; j++) acc[i][j] = z;

  const u16* wdb = wdt + (size_t)e * H_DIM * I_DIM;

  const u16* ga[4]; const u16* gb[4];
  u16 *la[4], *lb[4];
#pragma unroll
  for (int i = 0; i < 4; i++) {
    int c = tid + 256 * i;
    int row = c >> 3, kcl = c & 7;
    int kg = kcl ^ (row & 7);
    ga[i] = mid + (size_t)(off + row0 + row) * I_DIM + kg * 8;
    gb[i] = wdb + (size_t)(n0 + row) * I_DIM + kg * 8;
    la[i] = &As[c * 8]; lb[i] = &Bs[c * 8];
  }

  for (int kt = 0; kt < I_DIM / BK1; kt++) {
    const int k0 = kt * BK1;
#pragma unroll
    for (int i = 0; i < 4; i++) {
      async_ld16(ga[i] + k0, la[i]);
      async_ld16(gb[i] + k0, lb[i]);
    }
    __syncthreads();
#pragma unroll
    for (int kk = 0; kk < 2; kk++) {
      const int slot = ((kk << 2) + quad) ^ l7;
      short8 af[4];
#pragma unroll
      for (int im = 0; im < 4; im++)
        af[im] = *(const short8*)(&As[(wm + im * 16 + lr) * BK1 + slot * 8]);
#pragma unroll
      for (int in = 0; in < 4; in++) {
        short8 bf = *(const short8*)(&Bs[(wn + in * 16 + lr) * BK1 + slot * 8]);
#pragma unroll
        for (int im = 0; im < 4; im++)
          acc[im][in] = __builtin_amdgcn_mfma_f32_16x16x32_bf16(af[im], bf, acc[im][in], 0, 0, 0);
      }
    }
    __syncthreads();
  }

#pragma unroll
  for (int im = 0; im < 4; im++) {
#pragma unroll
    for (int r = 0; r < 4; r++) {
      int row = row0 + wm + im * 16 + quad * 4 + r;
      u16* orow = eout + (size_t)(off + row) * H_DIM + n0 + wn;
#pragma unroll
      for (int in = 0; in < 4; in++)
        orow[in * 16 + lr] = f2bf(acc[im][in][r]);
    }
  }
}

// ---------------- combine: out[t] = w0*eout[p0] + w1*eout[p1] ----------------
__global__ void combine_kernel(const u16* __restrict__ eout, const int* __restrict__ tpos,
                               const float* __restrict__ tw, float* __restrict__ out) {
  const int half = threadIdx.x >> 7;       // 2 tokens per block
  const int t = blockIdx.x * 2 + half;
  const int lt = threadIdx.x & 127;        // 128 threads per token, 8 cols each
  const int h0 = lt * 8;
  const int p0 = tpos[t * 2], p1 = tpos[t * 2 + 1];
  const float w0 = tw[t * 2], w1 = tw[t * 2 + 1];
  ushort4 a0 = *(const ushort4*)(eout + (size_t)p0 * H_DIM + h0);
  ushort4 a1 = *(const ushort4*)(eout + (size_t)p0 * H_DIM + h0 + 4);
  ushort4 b0 = *(const ushort4*)(eout + (size_t)p1 * H_DIM + h0);
  ushort4 b1 = *(const ushort4*)(eout + (size_t)p1 * H_DIM + h0 + 4);
  float4 o0, o1;
  o0.x = w0 * bf2f(a0.x) + w1 * bf2f(b0.x);
  o0.y = w0 * bf2f(a0.y) + w1 * bf2f(b0.y);
  o0.z = w0 * bf2f(a0.z) + w1 * bf2f(b0.z);
  o0.w = w0 * bf2f(a0.w) + w1 * bf2f(b0.w);
  o1.x = w0 * bf2f(a1.x) + w1 * bf2f(b1.x);
  o1.y = w0 * bf2f(a1.y) + w1 * bf2f(b1.y);
  o1.z = w0 * bf2f(a1.z) + w1 * bf2f(b1.z);
  o1.w = w0 * bf2f(a1.w) + w1 * bf2f(b1.w);
  float* orow = out + (size_t)t * H_DIM + h0;
  *(float4*)(orow) = o0;
  *(float4*)(orow + 4) = o1;
}

// ---------------- launch ----------------
extern "C" void kernel_launch(void* const* d_in, const int* in_sizes, int n_in,
                              void* d_out, int out_size, void* d_ws, size_t ws_size,
                              hipStream_t stream) {
  const float* x  = (const float*)d_in[0];   // [T, H]
  const float* gw = (const float*)d_in[1];   // [H, E]
  const float* Wg = (const float*)d_in[2];   // [E, H, I]
  const float* Wu = (const float*)d_in[3];   // [E, H, I]
  const float* Wd = (const float*)d_in[4];   // [E, I, H]
  float* out = (float*)d_out;                          // [T, H]
  float* out_logits = out + (size_t)T_TOK * H_DIM;     // [T, E]

  char* w = (char*)d_ws;
  size_t o = 0;
  auto take = [&](size_t bytes) { char* p = w + o; o += (bytes + 255) & ~(size_t)255; return p; };
  int*   counts      = (int*)take(E_NUM * 4);
  int*   offs        = (int*)take((E_NUM + 1) * 4);
  int*   cursor      = (int*)take(E_NUM * 4);
  int*   te          = (int*)take((size_t)T_TOK * 2 * 4);
  float* tw          = (float*)take((size_t)T_TOK * 2 * 4);
  int*   token_list  = (int*)take((size_t)PMAX * 4);
  int*   tpos        = (int*)take((size_t)T_TOK * 2 * 4);
  u16*   xb          = (u16*)take((size_t)T_TOK * H_DIM * 2);
  u16*   wgt         = (u16*)take((size_t)E_NUM * H_DIM * I_DIM * 2);  // [E][I][H] bf16
  u16*   wut         = (u16*)take((size_t)E_NUM * H_DIM * I_DIM * 2);  // [E][I][H] bf16
  u16*   wdt         = (u16*)take((size_t)E_NUM * H_DIM * I_DIM * 2);  // [E][H][I] bf16
  u16*   mid         = (u16*)take((size_t)PMAX * I_DIM * 2);           // [PMAX][I] bf16
  // eout aliases wgt: gemm1 (last reader of wgt) completes before gemm2 writes eout
  u16*   eout        = wgt;                                            // [PMAX][H] bf16 (19 MB < 32 MB)
  (void)in_sizes; (void)n_in; (void)out_size; (void)ws_size;

  prep_kernel<<<512, 256, 0, stream>>>(x, xb, T_TOK * H_DIM / 4, counts, token_list);
  wconv_kernel<<<dim3(E_NUM * 512, 1, 3), 256, 0, stream>>>(Wg, Wu, Wd, wgt, wut, wdt);
  router_kernel<<<T_TOK / 4, 256, 0, stream>>>(x, gw, out_logits, counts, te, tw);
  scan_kernel<<<1, 64, 0, stream>>>(counts, offs, cursor);
  scatter_kernel<<<T_TOK / 256, 256, 0, stream>>>(te, offs, cursor, token_list, tpos);
  gemm1_kernel<<<dim3(I_DIM / 128, PMAX / 128, E_NUM), 256, 0, stream>>>(xb, wgt, wut, token_list, offs, mid);
  gemm2_kernel<<<dim3(H_DIM / 128, PMAX / 128, E_NUM), 256, 0, stream>>>(mid, wdt, offs, eout);
  combine_kernel<<<T_TOK / 2, 256, 0, stream>>>(eout, tpos, tw, out);
}

// Round 5
// 420.074 us; speedup vs baseline: 1.5102x; 1.2798x over previous
//
#include <hip/hip_runtime.h>
#include <stdint.h>
#include <math.h>

#define T_TOK 4096
#define H_DIM 1024
#define I_DIM 2048
#define E_NUM 8
#define PMAX (T_TOK * 2 + E_NUM * 128)  // 9216 padded dispatch rows upper bound

typedef __attribute__((ext_vector_type(8))) short short8;
typedef __attribute__((ext_vector_type(4))) float f32x4;
typedef unsigned short u16;
typedef unsigned int u32;

__device__ __forceinline__ u16 f2bf(float f) {
  union { float f; u32 u; } v; v.f = f;
  u32 r = v.u + 0x7fffu + ((v.u >> 16) & 1u);  // round-to-nearest-even
  return (u16)(r >> 16);
}
__device__ __forceinline__ float bf2f(u16 a) {
  union { u32 u; float f; } v; v.u = ((u32)a) << 16; return v.f;
}

// async global->LDS DMA, 16 B per lane (m97 pattern; dest = wave base + lane*16)
__device__ __forceinline__ void async_ld16(const u16* g, u16* l) {
  __builtin_amdgcn_global_load_lds(
      (const __attribute__((address_space(1))) void*)g,
      (__attribute__((address_space(3))) void*)l, 16, 0, 0);
}

// ---------------- prep: convert x -> bf16, transpose gw -> gwT[8][1024] ----------------
__global__ void prep_kernel(const float* __restrict__ x, u16* __restrict__ xb,
                            const float* __restrict__ gw, float* __restrict__ gwT, int n4) {
  int i = blockIdx.x * blockDim.x + threadIdx.x;
  int stride = gridDim.x * blockDim.x;
  for (int j = i; j < n4; j += stride) {
    float4 v = ((const float4*)x)[j];
    ushort4 o;
    o.x = f2bf(v.x); o.y = f2bf(v.y); o.z = f2bf(v.z); o.w = f2bf(v.w);
    ((ushort4*)xb)[j] = o;
  }
  if (i < H_DIM * E_NUM) {
    int r = i >> 3, e = i & 7;
    gwT[e * H_DIM + r] = gw[i];
  }
}

// ---------------- fused weight transpose+convert (register 4x4 micro-transpose) ----------
__global__ void wconv_kernel(const float* __restrict__ Wg, const float* __restrict__ Wu,
                             const float* __restrict__ Wd, u16* __restrict__ wgt,
                             u16* __restrict__ wut, u16* __restrict__ wdt) {
  const int zz = blockIdx.z;
  const float* src = (zz == 0) ? Wg : (zz == 1) ? Wu : Wd;
  u16* dst = (zz == 0) ? wgt : (zz == 1) ? wut : wdt;
  const int R = (zz == 2) ? I_DIM : H_DIM;
  const int C = (zz == 2) ? H_DIM : I_DIM;
  const int cpt = C >> 6;
  const int e = blockIdx.x >> 9;
  const int ti = blockIdx.x & 511;
  const int r0 = (ti / cpt) << 6;
  const int c0 = (ti % cpt) << 6;
  const float* s = src + (size_t)e * H_DIM * I_DIM;
  u16* d = dst + (size_t)e * H_DIM * I_DIM;

  const int wave = threadIdx.x >> 6, lane = threadIdx.x & 63;
  const int g = lane >> 4, lq = lane & 15;
  const int c = c0 + wave * 16 + g * 4;
  const int r = r0 + lq * 4;

  float4 v0 = *(const float4*)(s + (size_t)(r + 0) * C + c);
  float4 v1 = *(const float4*)(s + (size_t)(r + 1) * C + c);
  float4 v2 = *(const float4*)(s + (size_t)(r + 2) * C + c);
  float4 v3 = *(const float4*)(s + (size_t)(r + 3) * C + c);

  ushort4 o;
  o.x = f2bf(v0.x); o.y = f2bf(v1.x); o.z = f2bf(v2.x); o.w = f2bf(v3.x);
  *(ushort4*)(d + (size_t)(c + 0) * R + r) = o;
  o.x = f2bf(v0.y); o.y = f2bf(v1.y); o.z = f2bf(v2.y); o.w = f2bf(v3.y);
  *(ushort4*)(d + (size_t)(c + 1) * R + r) = o;
  o.x = f2bf(v0.z); o.y = f2bf(v1.z); o.z = f2bf(v2.z); o.w = f2bf(v3.z);
  *(ushort4*)(d + (size_t)(c + 2) * R + r) = o;
  o.x = f2bf(v0.w); o.y = f2bf(v1.w); o.z = f2bf(v2.w); o.w = f2bf(v3.w);
  *(ushort4*)(d + (size_t)(c + 3) * R + r) = o;
}

// ---------------- router: logits, softmax, top-2 (one wave per token; NO atomics) --------
__global__ void router_kernel(const float* __restrict__ x, const float* __restrict__ gwT,
                              float* __restrict__ logits_out, int* __restrict__ te,
                              float* __restrict__ tw) {
  const int wave = threadIdx.x >> 6, lane = threadIdx.x & 63;
  const int t = blockIdx.x * 4 + wave;
  const float* xr = x + (size_t)t * H_DIM;
  float acc[8];
#pragma unroll
  for (int e = 0; e < 8; e++) acc[e] = 0.f;
#pragma unroll
  for (int it = 0; it < 4; it++) {
    int h0 = it * 256 + lane * 4;
    float4 xv = *(const float4*)(xr + h0);
#pragma unroll
    for (int e = 0; e < 8; e++) {
      float4 g = *(const float4*)(gwT + e * H_DIM + h0);  // lane-contiguous, coalesced
      acc[e] += xv.x * g.x + xv.y * g.y + xv.z * g.z + xv.w * g.w;
    }
  }
#pragma unroll
  for (int m = 1; m < 64; m <<= 1) {
#pragma unroll
    for (int e = 0; e < 8; e++) acc[e] += __shfl_xor(acc[e], m, 64);
  }
  if (lane == 0) {
    float mx = acc[0];
#pragma unroll
    for (int e = 1; e < 8; e++) mx = fmaxf(mx, acc[e]);
    float p[8]; float s = 0.f;
#pragma unroll
    for (int e = 0; e < 8; e++) { p[e] = __expf(acc[e] - mx); s += p[e]; }
    float inv = 1.0f / s;
    int e0 = 0; float b0 = acc[0];
#pragma unroll
    for (int e = 1; e < 8; e++) if (acc[e] > b0) { b0 = acc[e]; e0 = e; }
    int e1 = -1; float b1 = -1e30f;
#pragma unroll
    for (int e = 0; e < 8; e++) if (e != e0 && acc[e] > b1) { b1 = acc[e]; e1 = e; }
#pragma unroll
    for (int e = 0; e < 8; e++) logits_out[(size_t)t * 8 + e] = acc[e];
    te[t * 2] = e0; te[t * 2 + 1] = e1;
    tw[t * 2] = p[e0] * inv; tw[t * 2 + 1] = p[e1] * inv;
  }
}

// ---------------- sort: deterministic expert-bucket positions, single block, no atomics --
// 1024 threads x 4 tokens each. shfl intra-wave scan + LDS wave-total scan.
__global__ __launch_bounds__(1024) void sort_kernel(const int* __restrict__ te,
                                                    int* __restrict__ offs,
                                                    int* __restrict__ token_list,
                                                    int* __restrict__ tpos) {
  __shared__ int wsum[16][8];
  __shared__ int wbase[16][8];
  __shared__ int soffs[9];
  const int tid = threadIdx.x;
  const int wave = tid >> 6, lane = tid & 63;

  // default-fill token_list (padding rows -> token 0); real entries overwrite after barrier
  for (int j = tid; j < PMAX; j += 1024) token_list[j] = 0;

  const int t0 = tid * 4;
  int e_loc[8];
  int cnt[8];
#pragma unroll
  for (int e = 0; e < 8; e++) cnt[e] = 0;
#pragma unroll
  for (int k = 0; k < 8; k++) {
    int e = te[t0 * 2 + k];  // token t0 + (k>>1), pick k&1
    e_loc[k] = e;
    cnt[e]++;
  }
  // intra-wave inclusive scan per expert
  int excl[8];
#pragma unroll
  for (int e = 0; e < 8; e++) {
    int v = cnt[e];
    int s = v;
#pragma unroll
    for (int d = 1; d < 64; d <<= 1) {
      int u = __shfl_up(s, d, 64);
      if (lane >= d) s += u;
    }
    excl[e] = s - v;
    if (lane == 63) wsum[wave][e] = s;
  }
  __syncthreads();
  if (tid < 8) {
    int e = tid;
    int a = 0;
    for (int w2 = 0; w2 < 16; w2++) { wbase[w2][e] = a; a += wsum[w2][e]; }
    wsum[0][e] = a;  // total count for expert e
  }
  __syncthreads();
  if (tid == 0) {
    int a = 0;
    for (int e = 0; e < 8; e++) {
      soffs[e] = a;
      a += (wsum[0][e] + 127) & ~127;
    }
    soffs[8] = a;
    for (int e = 0; e <= 8; e++) offs[e] = soffs[e];
  }
  __syncthreads();
  int base[8];
#pragma unroll
  for (int e = 0; e < 8; e++) base[e] = soffs[e] + wbase[wave][e] + excl[e];
#pragma unroll
  for (int k = 0; k < 8; k++) {
    int e = e_loc[k];
    int pos = base[e]++;
    int t = t0 + (k >> 1);
    token_list[pos] = t;
    tpos[t * 2 + (k & 1)] = pos;
  }
}

// ---------------- GEMM1: mid = silu(Xe @ Wg) * (Xe @ Wu) ----------------
// 128x128 tile, BK=64, xor-swizzled LDS (swizzle applied on the global side of the DMA)
#define BK1 64

__global__ __launch_bounds__(256, 2) void gemm1_kernel(
    const u16* __restrict__ xb, const u16* __restrict__ wgt, const u16* __restrict__ wut,
    const int* __restrict__ token_list, const int* __restrict__ offs, u16* __restrict__ mid) {
  const int e = blockIdx.z;
  const int off = offs[e];
  const int pcount = offs[e + 1] - off;
  const int row0 = blockIdx.y * 128;
  if (row0 >= pcount) return;
  const int n0 = blockIdx.x * 128;

  __shared__ __align__(16) u16 As[128 * BK1];
  __shared__ __align__(16) u16 Bg[128 * BK1];
  __shared__ __align__(16) u16 Bu[128 * BK1];

  const int tid = threadIdx.x;
  const int wave = tid >> 6, lane = tid & 63;
  const int wm = (wave >> 1) * 64, wn = (wave & 1) * 64;
  const int quad = lane >> 4, lr = lane & 15;
  const int l7 = lr & 7;

  f32x4 accg[4][4], accu[4][4];
  f32x4 z = {0.f, 0.f, 0.f, 0.f};
#pragma unroll
  for (int i = 0; i < 4; i++)
#pragma unroll
    for (int j = 0; j < 4; j++) { accg[i][j] = z; accu[i][j] = z; }

  const u16* wgb = wgt + (size_t)e * I_DIM * H_DIM;
  const u16* wub = wut + (size_t)e * I_DIM * H_DIM;

  const u16* ga[4]; const u16* gg[4]; const u16* gu[4];
  u16 *la[4], *lg[4], *lu[4];
#pragma unroll
  for (int i = 0; i < 4; i++) {
    int c = tid + 256 * i;
    int row = c >> 3, kcl = c & 7;
    int kg = kcl ^ (row & 7);
    int tok = token_list[off + row0 + row];  // padded rows -> token 0 (harmless)
    ga[i] = xb + (size_t)tok * H_DIM + kg * 8;
    gg[i] = wgb + (size_t)(n0 + row) * H_DIM + kg * 8;
    gu[i] = wub + (size_t)(n0 + row) * H_DIM + kg * 8;
    la[i] = &As[c * 8]; lg[i] = &Bg[c * 8]; lu[i] = &Bu[c * 8];
  }

  for (int kt = 0; kt < H_DIM / BK1; kt++) {
    const int k0 = kt * BK1;
#pragma unroll
    for (int i = 0; i < 4; i++) {
      async_ld16(ga[i] + k0, la[i]);
      async_ld16(gg[i] + k0, lg[i]);
      async_ld16(gu[i] + k0, lu[i]);
    }
    __syncthreads();
#pragma unroll
    for (int kk = 0; kk < 2; kk++) {
      const int slot = ((kk << 2) + quad) ^ l7;
      short8 af[4];
#pragma unroll
      for (int im = 0; im < 4; im++)
        af[im] = *(const short8*)(&As[(wm + im * 16 + lr) * BK1 + slot * 8]);
#pragma unroll
      for (int in = 0; in < 4; in++) {
        short8 bg = *(const short8*)(&Bg[(wn + in * 16 + lr) * BK1 + slot * 8]);
        short8 bu = *(const short8*)(&Bu[(wn + in * 16 + lr) * BK1 + slot * 8]);
#pragma unroll
        for (int im = 0; im < 4; im++) {
          accg[im][in] = __builtin_amdgcn_mfma_f32_16x16x32_bf16(af[im], bg, accg[im][in], 0, 0, 0);
          accu[im][in] = __builtin_amdgcn_mfma_f32_16x16x32_bf16(af[im], bu, accu[im][in], 0, 0, 0);
        }
      }
    }
    __syncthreads();
  }

#pragma unroll
  for (int im = 0; im < 4; im++) {
#pragma unroll
    for (int r = 0; r < 4; r++) {
      int row = row0 + wm + im * 16 + quad * 4 + r;
      u16* mrow = mid + (size_t)(off + row) * I_DIM + n0 + wn;
#pragma unroll
      for (int in = 0; in < 4; in++) {
        float g = accg[im][in][r];
        float u = accu[im][in][r];
        float sv = g / (1.0f + __expf(-g)) * u;  // silu(g) * u
        mrow[in * 16 + lr] = f2bf(sv);
      }
    }
  }
}

// ---------------- GEMM2: eout = mid @ Wd^T  (dense bf16 store, no atomics) ----------------
__global__ __launch_bounds__(256, 2) void gemm2_kernel(
    const u16* __restrict__ mid, const u16* __restrict__ wdt,
    const int* __restrict__ offs, u16* __restrict__ eout) {
  const int e = blockIdx.z;
  const int off = offs[e];
  const int pcount = offs[e + 1] - off;
  const int row0 = blockIdx.y * 128;
  if (row0 >= pcount) return;
  const int n0 = blockIdx.x * 128;

  __shared__ __align__(16) u16 As[128 * BK1];
  __shared__ __align__(16) u16 Bs[128 * BK1];

  const int tid = threadIdx.x;
  const int wave = tid >> 6, lane = tid & 63;
  const int wm = (wave >> 1) * 64, wn = (wave & 1) * 64;
  const int quad = lane >> 4, lr = lane & 15;
  const int l7 = lr & 7;

  f32x4 acc[4][4];
  f32x4 z = {0.f, 0.f, 0.f, 0.f};
#pragma unroll
  for (int i = 0; i < 4; i++)
#pragma unroll
    for (int j = 0; j < 4; j++) acc[i][j] = z;

  const u16* wdb = wdt + (size_t)e * H_DIM * I_DIM;

  const u16* ga[4]; const u16* gb[4];
  u16 *la[4], *lb[4];
#pragma unroll
  for (int i = 0; i < 4; i++) {
    int c = tid + 256 * i;
    int row = c >> 3, kcl = c & 7;
    int kg = kcl ^ (row & 7);
    ga[i] = mid + (size_t)(off + row0 + row) * I_DIM + kg * 8;
    gb[i] = wdb + (size_t)(n0 + row) * I_DIM + kg * 8;
    la[i] = &As[c * 8]; lb[i] = &Bs[c * 8];
  }

  for (int kt = 0; kt < I_DIM / BK1; kt++) {
    const int k0 = kt * BK1;
#pragma unroll
    for (int i = 0; i < 4; i++) {
      async_ld16(ga[i] + k0, la[i]);
      async_ld16(gb[i] + k0, lb[i]);
    }
    __syncthreads();
#pragma unroll
    for (int kk = 0; kk < 2; kk++) {
      const int slot = ((kk << 2) + quad) ^ l7;
      short8 af[4];
#pragma unroll
      for (int im = 0; im < 4; im++)
        af[im] = *(const short8*)(&As[(wm + im * 16 + lr) * BK1 + slot * 8]);
#pragma unroll
      for (int in = 0; in < 4; in++) {
        short8 bf = *(const short8*)(&Bs[(wn + in * 16 + lr) * BK1 + slot * 8]);
#pragma unroll
        for (int im = 0; im < 4; im++)
          acc[im][in] = __builtin_amdgcn_mfma_f32_16x16x32_bf16(af[im], bf, acc[im][in], 0, 0, 0);
      }
    }
    __syncthreads();
  }

#pragma unroll
  for (int im = 0; im < 4; im++) {
#pragma unroll
    for (int r = 0; r < 4; r++) {
      int row = row0 + wm + im * 16 + quad * 4 + r;
      u16* orow = eout + (size_t)(off + row) * H_DIM + n0 + wn;
#pragma unroll
      for (int in = 0; in < 4; in++)
        orow[in * 16 + lr] = f2bf(acc[im][in][r]);
    }
  }
}

// ---------------- combine: out[t] = w0*eout[p0] + w1*eout[p1] ----------------
__global__ void combine_kernel(const u16* __restrict__ eout, const int* __restrict__ tpos,
                               const float* __restrict__ tw, float* __restrict__ out) {
  const int half = threadIdx.x >> 7;
  const int t = blockIdx.x * 2 + half;
  const int lt = threadIdx.x & 127;
  const int h0 = lt * 8;
  const int p0 = tpos[t * 2], p1 = tpos[t * 2 + 1];
  const float w0 = tw[t * 2], w1 = tw[t * 2 + 1];
  ushort4 a0 = *(const ushort4*)(eout + (size_t)p0 * H_DIM + h0);
  ushort4 a1 = *(const ushort4*)(eout + (size_t)p0 * H_DIM + h0 + 4);
  ushort4 b0 = *(const ushort4*)(eout + (size_t)p1 * H_DIM + h0);
  ushort4 b1 = *(const ushort4*)(eout + (size_t)p1 * H_DIM + h0 + 4);
  float4 o0, o1;
  o0.x = w0 * bf2f(a0.x) + w1 * bf2f(b0.x);
  o0.y = w0 * bf2f(a0.y) + w1 * bf2f(b0.y);
  o0.z = w0 * bf2f(a0.z) + w1 * bf2f(b0.z);
  o0.w = w0 * bf2f(a0.w) + w1 * bf2f(b0.w);
  o1.x = w0 * bf2f(a1.x) + w1 * bf2f(b1.x);
  o1.y = w0 * bf2f(a1.y) + w1 * bf2f(b1.y);
  o1.z = w0 * bf2f(a1.z) + w1 * bf2f(b1.z);
  o1.w = w0 * bf2f(a1.w) + w1 * bf2f(b1.w);
  float* orow = out + (size_t)t * H_DIM + h0;
  *(float4*)(orow) = o0;
  *(float4*)(orow + 4) = o1;
}

// ---------------- launch ----------------
extern "C" void kernel_launch(void* const* d_in, const int* in_sizes, int n_in,
                              void* d_out, int out_size, void* d_ws, size_t ws_size,
                              hipStream_t stream) {
  const float* x  = (const float*)d_in[0];   // [T, H]
  const float* gw = (const float*)d_in[1];   // [H, E]
  const float* Wg = (const float*)d_in[2];   // [E, H, I]
  const float* Wu = (const float*)d_in[3];   // [E, H, I]
  const float* Wd = (const float*)d_in[4];   // [E, I, H]
  float* out = (float*)d_out;                          // [T, H]
  float* out_logits = out + (size_t)T_TOK * H_DIM;     // [T, E]

  char* w = (char*)d_ws;
  size_t o = 0;
  auto take = [&](size_t bytes) { char* p = w + o; o += (bytes + 255) & ~(size_t)255; return p; };
  int*   offs        = (int*)take((E_NUM + 1) * 4);
  int*   te          = (int*)take((size_t)T_TOK * 2 * 4);
  float* tw          = (float*)take((size_t)T_TOK * 2 * 4);
  int*   token_list  = (int*)take((size_t)PMAX * 4);
  int*   tpos        = (int*)take((size_t)T_TOK * 2 * 4);
  float* gwT         = (float*)take((size_t)E_NUM * H_DIM * 4);
  u16*   xb          = (u16*)take((size_t)T_TOK * H_DIM * 2);
  u16*   wgt         = (u16*)take((size_t)E_NUM * H_DIM * I_DIM * 2);  // [E][I][H] bf16
  u16*   wut         = (u16*)take((size_t)E_NUM * H_DIM * I_DIM * 2);  // [E][I][H] bf16
  u16*   wdt         = (u16*)take((size_t)E_NUM * H_DIM * I_DIM * 2);  // [E][H][I] bf16
  u16*   mid         = (u16*)take((size_t)PMAX * I_DIM * 2);           // [PMAX][I] bf16
  // eout aliases wgt: gemm1 (last reader of wgt) completes before gemm2 writes eout
  u16*   eout        = wgt;                                            // [PMAX][H] bf16
  (void)in_sizes; (void)n_in; (void)out_size; (void)ws_size;

  prep_kernel<<<512, 256, 0, stream>>>(x, xb, gw, gwT, T_TOK * H_DIM / 4);
  wconv_kernel<<<dim3(E_NUM * 512, 1, 3), 256, 0, stream>>>(Wg, Wu, Wd, wgt, wut, wdt);
  router_kernel<<<T_TOK / 4, 256, 0, stream>>>(x, gwT, out_logits, te, tw);
  sort_kernel<<<1, 1024, 0, stream>>>(te, offs, token_list, tpos);
  gemm1_kernel<<<dim3(I_DIM / 128, PMAX / 128, E_NUM), 256, 0, stream>>>(xb, wgt, wut, token_list, offs, mid);
  gemm2_kernel<<<dim3(H_DIM / 128, PMAX / 128, E_NUM), 256, 0, stream>>>(mid, wdt, offs, eout);
  combine_kernel<<<T_TOK / 2, 256, 0, stream>>>(eout, tpos, tw, out);
}